// Round 1
// baseline (174.156 us; speedup 1.0000x reference)
//
#include <hip/hip_runtime.h>
#include <hip/hip_bf16.h>
#include <cstdint>
#include <cstddef>

// Problem constants
#define BB   2
#define SS   2048
#define DD   512
#define HH   8
#define HDIM 64

typedef __attribute__((ext_vector_type(8))) short          s16x8;
typedef __attribute__((ext_vector_type(8))) unsigned short u16x8;
typedef __attribute__((ext_vector_type(4))) float          f32x4;

static __device__ __forceinline__ unsigned short f2bf(float f) {
  union { float f; unsigned u; } x; x.f = f;
  unsigned r = x.u + 0x7fffu + ((x.u >> 16) & 1u);  // RNE
  return (unsigned short)(r >> 16);
}

// ---------------- fp32 -> bf16 conversion (exact-sized grid, 4 elems/thread) ---------
__global__ __launch_bounds__(256) void cvt_kernel(const float* __restrict__ src,
                                                  unsigned short* __restrict__ dst) {
  int i = (blockIdx.x * 256 + threadIdx.x) * 4;
  float4 f = *(const float4*)(src + i);
  ushort4 o;
  o.x = f2bf(f.x); o.y = f2bf(f.y); o.z = f2bf(f.z); o.w = f2bf(f.w);
  *(ushort4*)(dst + i) = o;
}

// ---------------- QKV projection: [4096x512] @ [512x512]^T, NT GEMM -----------------
// grid (M/128, N/128, 3); 256 threads = 4 waves in 2x2; 16x16x32 bf16 MFMA.
// Output written as bf16 in head-split layout [B][H][S][HDIM].
__global__ __launch_bounds__(256) void proj_kernel(
    const unsigned short* __restrict__ xb,
    const unsigned short* __restrict__ wqb,
    const unsigned short* __restrict__ wkb,
    const unsigned short* __restrict__ wvb,
    const float* __restrict__ bq, const float* __restrict__ bk, const float* __restrict__ bv,
    unsigned short* __restrict__ qo, unsigned short* __restrict__ ko,
    unsigned short* __restrict__ vo) {
  __shared__ unsigned short As[128 * 40];  // pad 32->40 bf16: 2-way-max bank aliasing
  __shared__ unsigned short Bs[128 * 40];

  const unsigned short* wb; const float* bias; unsigned short* dst;
  if (blockIdx.z == 0)      { wb = wqb; bias = bq; dst = qo; }
  else if (blockIdx.z == 1) { wb = wkb; bias = bk; dst = ko; }
  else                      { wb = wvb; bias = bv; dst = vo; }

  const int t = threadIdx.x;
  const int lane = t & 63, wave = t >> 6;
  const int quad = lane >> 4, lq = lane & 15;
  const int wr = wave >> 1, wc = wave & 1;
  const int m0 = blockIdx.x * 128, n0 = blockIdx.y * 128;

  f32x4 acc[4][4] = {};

  for (int k0 = 0; k0 < DD; k0 += 32) {
    __syncthreads();
    // stage 128x32 A and B tiles (512 x 16B chunks each, 2 per thread per array)
    for (int c = t; c < 512; c += 256) {
      int row = c >> 2, c8 = (c & 3) * 8;
      *(u16x8*)&As[row * 40 + c8] = *(const u16x8*)&xb[(size_t)(m0 + row) * DD + k0 + c8];
      *(u16x8*)&Bs[row * 40 + c8] = *(const u16x8*)&wb[(size_t)(n0 + row) * DD + k0 + c8];
    }
    __syncthreads();
    s16x8 a[4], b[4];
#pragma unroll
    for (int mi = 0; mi < 4; mi++)
      a[mi] = *(const s16x8*)&As[(wr * 64 + mi * 16 + lq) * 40 + quad * 8];
#pragma unroll
    for (int ni = 0; ni < 4; ni++)
      b[ni] = *(const s16x8*)&Bs[(wc * 64 + ni * 16 + lq) * 40 + quad * 8];
#pragma unroll
    for (int mi = 0; mi < 4; mi++)
#pragma unroll
      for (int ni = 0; ni < 4; ni++)
        acc[mi][ni] = __builtin_amdgcn_mfma_f32_16x16x32_bf16(a[mi], b[ni], acc[mi][ni], 0, 0, 0);
  }

  // Epilogue: C/D layout col = lane&15, row = quad*4 + r. Add bias, bf16, head-split store.
#pragma unroll
  for (int ni = 0; ni < 4; ni++) {
    int col = n0 + wc * 64 + ni * 16 + lq;
    float bval = bias[col];
    int h = col >> 6, hd = col & 63;
#pragma unroll
    for (int mi = 0; mi < 4; mi++) {
#pragma unroll
      for (int r = 0; r < 4; r++) {
        int row = m0 + wr * 64 + mi * 16 + quad * 4 + r;
        int bidx = row >> 11, s = row & 2047;
        dst[(((size_t)(bidx * HH + h) * SS) + s) * HDIM + hd] = f2bf(acc[mi][ni][r] + bval);
      }
    }
  }
}

// ---------------- fused sigmoid attention -------------------------------------------
// grid (S/64, H, B); 256 threads = 4 waves; each wave owns 16 queries.
// Per 64-key tile: stage K (row-major) + V (transposed) in LDS;
// S^T = K·Q^T via MFMA (m=key, n=query) -> sigmoid -> P to LDS in A-layout
// -> O += P·V via MFMA (m=query, n=d, k=key).
__global__ __launch_bounds__(256) void attn_kernel(
    const unsigned short* __restrict__ qb,
    const unsigned short* __restrict__ kb,
    const unsigned short* __restrict__ vb,
    float* __restrict__ out) {
  __shared__ unsigned short ks[64 * 72];      // K tile  [key][d], padded
  __shared__ unsigned short vT[64 * 72];      // V tile  [d][key], padded
  __shared__ unsigned short pb[4 * 16 * 72];  // per-wave P  [q][key], padded

  const int t = threadIdx.x;
  const int lane = t & 63, wave = t >> 6;
  const int quad = lane >> 4, lq = lane & 15;
  const int b = blockIdx.z, h = blockIdx.y;
  const int bh = b * HH + h;
  const unsigned short* qh = qb + (size_t)bh * SS * HDIM;
  const unsigned short* kh = kb + (size_t)bh * SS * HDIM;
  const unsigned short* vh = vb + (size_t)bh * SS * HDIM;
  const int q0 = blockIdx.x * 64;
  const int qrow = q0 + wave * 16 + lq;

  // Q fragments (B-operand: n = lane&15 = query, k = d): live for whole kernel
  s16x8 qf0 = *(const s16x8*)&qh[(size_t)qrow * HDIM + quad * 8];
  s16x8 qf1 = *(const s16x8*)&qh[(size_t)qrow * HDIM + 32 + quad * 8];

  f32x4 o[4] = {};
  unsigned short* pw = &pb[wave * 16 * 72];

  for (int k0 = 0; k0 < SS; k0 += 64) {
    __syncthreads();
    // stage 64x64 K and V tiles; V stored transposed for the B-operand of PV
    for (int c = t; c < 512; c += 256) {
      int row = c >> 3, c8 = (c & 7) * 8;
      *(u16x8*)&ks[row * 72 + c8] = *(const u16x8*)&kh[(size_t)(k0 + row) * HDIM + c8];
      u16x8 vv = *(const u16x8*)&vh[(size_t)(k0 + row) * HDIM + c8];
#pragma unroll
      for (int j = 0; j < 8; j++) vT[(c8 + j) * 72 + row] = vv[j];
    }
    __syncthreads();

    // S^T tiles: 4 key 16-tiles x 1 query 16-tile, contraction over d (2 chunks of 32)
    f32x4 st[4] = {};
#pragma unroll
    for (int c = 0; c < 2; c++) {
      s16x8 qc = c ? qf1 : qf0;
#pragma unroll
      for (int mk = 0; mk < 4; mk++) {
        s16x8 kf = *(const s16x8*)&ks[(mk * 16 + lq) * 72 + c * 32 + quad * 8];
        st[mk] = __builtin_amdgcn_mfma_f32_16x16x32_bf16(kf, qc, st[mk], 0, 0, 0);
      }
    }

    // sigmoid(score/8), pack to bf16 pairs, write P to per-wave LDS:
    // C-layout here: m=key = quad*4+r, n=query = lq  ->  pw[q][key]
#pragma unroll
    for (int mk = 0; mk < 4; mk++) {
      float p0 = 1.0f / (1.0f + __expf(-st[mk][0] * 0.125f));
      float p1 = 1.0f / (1.0f + __expf(-st[mk][1] * 0.125f));
      float p2 = 1.0f / (1.0f + __expf(-st[mk][2] * 0.125f));
      float p3 = 1.0f / (1.0f + __expf(-st[mk][3] * 0.125f));
      unsigned p01 = (unsigned)f2bf(p0) | ((unsigned)f2bf(p1) << 16);
      unsigned p23 = (unsigned)f2bf(p2) | ((unsigned)f2bf(p3) << 16);
      *(unsigned*)&pw[lq * 72 + mk * 16 + quad * 4]     = p01;
      *(unsigned*)&pw[lq * 72 + mk * 16 + quad * 4 + 2] = p23;
    }
    __syncthreads();

    // PV: O[q][d] += sum_key P[q][key] * vT[d][key]
#pragma unroll
    for (int c = 0; c < 2; c++) {
      s16x8 pf = *(const s16x8*)&pw[lq * 72 + c * 32 + quad * 8];
#pragma unroll
      for (int nd = 0; nd < 4; nd++) {
        s16x8 vf = *(const s16x8*)&vT[(nd * 16 + lq) * 72 + c * 32 + quad * 8];
        o[nd] = __builtin_amdgcn_mfma_f32_16x16x32_bf16(pf, vf, o[nd], 0, 0, 0);
      }
    }
  }

  // O in C-layout: m=query = quad*4+r, n=d = lq. Merge heads -> out[b][s][h*64+d]
  const int srow = q0 + wave * 16 + quad * 4;
#pragma unroll
  for (int nd = 0; nd < 4; nd++) {
#pragma unroll
    for (int r = 0; r < 4; r++) {
      out[((size_t)(b * SS + srow + r)) * DD + h * HDIM + nd * 16 + lq] = o[nd][r];
    }
  }
}

extern "C" void kernel_launch(void* const* d_in, const int* in_sizes, int n_in,
                              void* d_out, int out_size, void* d_ws, size_t ws_size,
                              hipStream_t stream) {
  const float* x  = (const float*)d_in[0];
  const float* wq = (const float*)d_in[1];
  const float* bq = (const float*)d_in[2];
  const float* wk = (const float*)d_in[3];
  const float* bk = (const float*)d_in[4];
  const float* wv = (const float*)d_in[5];
  const float* bv = (const float*)d_in[6];
  float* out = (float*)d_out;

  constexpr size_t XN = (size_t)BB * SS * DD;  // 2,097,152
  constexpr size_t WN = (size_t)DD * DD;       //   262,144
  constexpr size_t QN = XN;

  unsigned short* base = (unsigned short*)d_ws;
  unsigned short* xb  = base;
  unsigned short* wqb = xb + XN;
  unsigned short* wkb = wqb + WN;
  unsigned short* wvb = wkb + WN;
  unsigned short* qo  = wvb + WN;
  unsigned short* ko  = qo + QN;
  unsigned short* vo  = ko + QN;
  // total ws use: (XN + 3*WN + 3*QN) * 2 bytes ~= 17.5 MB

  cvt_kernel<<<XN / 1024, 256, 0, stream>>>(x, xb);
  cvt_kernel<<<WN / 1024, 256, 0, stream>>>(wq, wqb);
  cvt_kernel<<<WN / 1024, 256, 0, stream>>>(wk, wkb);
  cvt_kernel<<<WN / 1024, 256, 0, stream>>>(wv, wvb);

  proj_kernel<<<dim3(32, 4, 3), 256, 0, stream>>>(xb, wqb, wkb, wvb, bq, bk, bv, qo, ko, vo);

  attn_kernel<<<dim3(SS / 64, HH, BB), 256, 0, stream>>>(qo, ko, vo, out);
}

// Round 2
// 144.858 us; speedup vs baseline: 1.2023x; 1.2023x over previous
//
#include <hip/hip_runtime.h>
#include <cstdint>
#include <cstddef>

// Problem constants
#define BB   2
#define SS   2048
#define DD   512
#define HH   8
#define HDIM 64

typedef __attribute__((ext_vector_type(8)))  short          s16x8;
typedef __attribute__((ext_vector_type(8)))  unsigned short u16x8;
typedef __attribute__((ext_vector_type(4)))  float          f32x4;
typedef __attribute__((ext_vector_type(16))) float          f32x16;

static __device__ __forceinline__ unsigned short f2bf(float f) {
  union { float f; unsigned u; } x; x.f = f;
  unsigned r = x.u + 0x7fffu + ((x.u >> 16) & 1u);  // RNE
  return (unsigned short)(r >> 16);
}

// ---------------- fused cvt + QKV projection: [4096x512] @ [512x512]^T --------------
// Reads fp32 x/w directly, converts to bf16 while staging (no separate cvt pass).
// grid (M/128, N/128, 3); 256 threads = 4 waves in 2x2; 16x16x32 bf16 MFMA.
// q,k written bf16 head-split [B][H][S][HD]; v written TRANSPOSED [B][H][HD][S]
// so attn never transposes in LDS. Q is pre-scaled by 1/sqrt(HD)=0.125.
__global__ __launch_bounds__(256) void proj_kernel(
    const float* __restrict__ x,
    const float* __restrict__ wq, const float* __restrict__ wk, const float* __restrict__ wv,
    const float* __restrict__ bq, const float* __restrict__ bk, const float* __restrict__ bv,
    unsigned short* __restrict__ qo, unsigned short* __restrict__ ko,
    unsigned short* __restrict__ vt) {
  __shared__ unsigned short As[128 * 40];  // pad 32->40 bf16
  __shared__ unsigned short Bs[128 * 40];

  const float* w; const float* bias;
  if (blockIdx.z == 0)      { w = wq; bias = bq; }
  else if (blockIdx.z == 1) { w = wk; bias = bk; }
  else                      { w = wv; bias = bv; }

  const int t = threadIdx.x;
  const int lane = t & 63, wave = t >> 6;
  const int quad = lane >> 4, lq = lane & 15;
  const int wr = wave >> 1, wc = wave & 1;
  const int m0 = blockIdx.x * 128, n0 = blockIdx.y * 128;

  f32x4 acc[4][4] = {};

  for (int k0 = 0; k0 < DD; k0 += 32) {
    __syncthreads();
    // stage 128x32 fp32 tiles of A=x and B=w, converting to bf16 in-register
    for (int c = t; c < 1024; c += 256) {
      int row = c >> 3, c4 = (c & 7) * 4;
      float4 fa = *(const float4*)&x[(size_t)(m0 + row) * DD + k0 + c4];
      float4 fb = *(const float4*)&w[(size_t)(n0 + row) * DD + k0 + c4];
      ushort4 ua, ub;
      ua.x = f2bf(fa.x); ua.y = f2bf(fa.y); ua.z = f2bf(fa.z); ua.w = f2bf(fa.w);
      ub.x = f2bf(fb.x); ub.y = f2bf(fb.y); ub.z = f2bf(fb.z); ub.w = f2bf(fb.w);
      *(ushort4*)&As[row * 40 + c4] = ua;
      *(ushort4*)&Bs[row * 40 + c4] = ub;
    }
    __syncthreads();
    s16x8 a[4], b[4];
#pragma unroll
    for (int mi = 0; mi < 4; mi++)
      a[mi] = *(const s16x8*)&As[(wr * 64 + mi * 16 + lq) * 40 + quad * 8];
#pragma unroll
    for (int ni = 0; ni < 4; ni++)
      b[ni] = *(const s16x8*)&Bs[(wc * 64 + ni * 16 + lq) * 40 + quad * 8];
#pragma unroll
    for (int mi = 0; mi < 4; mi++)
#pragma unroll
      for (int ni = 0; ni < 4; ni++)
        acc[mi][ni] = __builtin_amdgcn_mfma_f32_16x16x32_bf16(a[mi], b[ni], acc[mi][ni], 0, 0, 0);
  }

  // Epilogue: C/D layout col = lane&15, row = quad*4 + r.
  const float scale = (blockIdx.z == 0) ? 0.125f : 1.0f;  // fold 1/sqrt(64) into Q
  unsigned short* dst = (blockIdx.z == 0) ? qo : ko;
#pragma unroll
  for (int ni = 0; ni < 4; ni++) {
    int col = n0 + wc * 64 + ni * 16 + lq;
    float bval = bias[col];
    int h = col >> 6, hd = col & 63;
#pragma unroll
    for (int mi = 0; mi < 4; mi++) {
#pragma unroll
      for (int r = 0; r < 4; r++) {
        int row = m0 + wr * 64 + mi * 16 + quad * 4 + r;
        int bidx = row >> 11, s = row & 2047;
        unsigned short v = f2bf((acc[mi][ni][r] + bval) * scale);
        if (blockIdx.z < 2)
          dst[(((size_t)(bidx * HH + h) * SS) + s) * HDIM + hd] = v;
        else  // V stored transposed: [B][H][HD][S]
          vt[(((size_t)(bidx * HH + h) * HDIM) + hd) * SS + s] = v;
      }
    }
  }
}

// ---------------- fused sigmoid attention (32x32x16 MFMA) ---------------------------
// grid (S/64, B*H); 256 threads = 4 waves: wave = (qhalf, khalf), 32q x 32k each.
// Per 64-key tile: reg-prefetched K [key][d] + V^T [d][key] staged to LDS with b128;
// S^T = K.Q^T (m=key,n=q) -> sigmoid -> P[q][key] per-wave LDS -> O += P.V^T.
// Cross-wave (khalf) O reduction through LDS at the end.
__global__ __launch_bounds__(256) void attn_kernel(
    const unsigned short* __restrict__ qb,
    const unsigned short* __restrict__ kb,
    const unsigned short* __restrict__ vtb,
    float* __restrict__ out) {
  __shared__ unsigned short smem[64 * 72 + 64 * 72 + 4 * 32 * 40];  // 28672 B
  unsigned short* ks = smem;               // K tile [key][d], pad 72
  unsigned short* vs = smem + 64 * 72;     // V^T tile [d][key], pad 72
  unsigned short* pbase = smem + 2 * 64 * 72;  // P per wave [32q][32k], pad 40
  float* red = (float*)smem;               // 16 KB alias for O reduction

  const int t = threadIdx.x;
  const int lane = t & 63, wave = t >> 6;
  const int ln = lane & 31, hi = lane >> 5;
  const int qh = wave & 1, kh = wave >> 1;
  const int bh = blockIdx.y;
  const int b = bh >> 3, h = bh & 7;
  const unsigned short* qp = qb + (size_t)bh * SS * HDIM;
  const unsigned short* kp = kb + (size_t)bh * SS * HDIM;
  const unsigned short* vp = vtb + (size_t)bh * HDIM * SS;
  const int q0 = blockIdx.x * 64;

  // Q fragments, whole kernel in regs: B[n=q][k=d], q = q0+qh*32+ln, d = c*16+hi*8+j
  s16x8 qf[4];
  {
    const int qrow = q0 + qh * 32 + ln;
#pragma unroll
    for (int c = 0; c < 4; c++)
      qf[c] = *(const s16x8*)&qp[(size_t)qrow * HDIM + c * 16 + hi * 8];
  }

  unsigned short* pw = pbase + wave * (32 * 40);
  f32x16 o0 = {}, o1 = {};

  // register double-buffered staging: thread owns chunks {t, t+256} of 512 per array
  u16x8 kr[2][2], vr[2][2];
#pragma unroll
  for (int i = 0; i < 2; i++) {
    int c = t + i * 256;
    int row = c >> 3, off = (c & 7) * 8;
    kr[0][i] = *(const u16x8*)&kp[(size_t)row * HDIM + off];
    vr[0][i] = *(const u16x8*)&vp[(size_t)row * SS + off];
  }

#pragma unroll 2
  for (int kt = 0; kt < 32; kt++) {
    const int cur = kt & 1, nxt = cur ^ 1;
    __syncthreads();  // prev-iter LDS reads complete
#pragma unroll
    for (int i = 0; i < 2; i++) {
      int c = t + i * 256;
      int row = c >> 3, off = (c & 7) * 8;
      *(u16x8*)&ks[row * 72 + off] = kr[cur][i];
      *(u16x8*)&vs[row * 72 + off] = vr[cur][i];
    }
    if (kt < 31) {  // prefetch next tile into the other register buffer
      int k0n = (kt + 1) * 64;
#pragma unroll
      for (int i = 0; i < 2; i++) {
        int c = t + i * 256;
        int row = c >> 3, off = (c & 7) * 8;
        kr[nxt][i] = *(const u16x8*)&kp[(size_t)(k0n + row) * HDIM + off];
        vr[nxt][i] = *(const u16x8*)&vp[(size_t)row * SS + k0n + off];
      }
    }
    __syncthreads();

    // QK^T: st = S^T[key = kh*32 + rowpat][q = qh*32 + ln]
    f32x16 st = {};
#pragma unroll
    for (int c = 0; c < 4; c++) {
      s16x8 kf = *(const s16x8*)&ks[(kh * 32 + ln) * 72 + c * 16 + hi * 8];
      st = __builtin_amdgcn_mfma_f32_32x32x16_bf16(kf, qf[c], st, 0, 0, 0);
    }

    // sigmoid (scale pre-folded into Q) -> P[q=ln][key_local], packed b64 writes
    // C layout: key_local = (r&3) + 8*(r>>2) + 4*hi
#pragma unroll
    for (int g = 0; g < 4; g++) {
      ushort4 pk;
      float e0 = __expf(-st[4 * g + 0]);
      float e1 = __expf(-st[4 * g + 1]);
      float e2 = __expf(-st[4 * g + 2]);
      float e3 = __expf(-st[4 * g + 3]);
      pk.x = f2bf(__builtin_amdgcn_rcpf(1.0f + e0));
      pk.y = f2bf(__builtin_amdgcn_rcpf(1.0f + e1));
      pk.z = f2bf(__builtin_amdgcn_rcpf(1.0f + e2));
      pk.w = f2bf(__builtin_amdgcn_rcpf(1.0f + e3));
      *(ushort4*)&pw[ln * 40 + g * 8 + hi * 4] = pk;
    }
    // P is per-wave private; in-wave LDS write->read needs only an lgkm drain
    asm volatile("s_waitcnt lgkmcnt(0)" ::: "memory");

    // PV: O[q][d] += P[q][key] * V^T[d][key], contraction over this wave's 32 keys
#pragma unroll
    for (int c = 0; c < 2; c++) {
      s16x8 pf  = *(const s16x8*)&pw[ln * 40 + c * 16 + hi * 8];
      s16x8 vf0 = *(const s16x8*)&vs[(ln) * 72 + kh * 32 + c * 16 + hi * 8];
      s16x8 vf1 = *(const s16x8*)&vs[(32 + ln) * 72 + kh * 32 + c * 16 + hi * 8];
      o0 = __builtin_amdgcn_mfma_f32_32x32x16_bf16(pf, vf0, o0, 0, 0, 0);
      o1 = __builtin_amdgcn_mfma_f32_32x32x16_bf16(pf, vf1, o1, 0, 0, 0);
    }
  }

  // reduce O over khalf pairs through LDS (aliases ks/vs — dead now)
  __syncthreads();
  if (kh == 1) {
#pragma unroll
    for (int r = 0; r < 16; r++) {
      int q = (r & 3) + 8 * (r >> 2) + 4 * hi;
      red[qh * 2048 + q * 64 + ln] = o0[r];
      red[qh * 2048 + q * 64 + 32 + ln] = o1[r];
    }
  }
  __syncthreads();
  if (kh == 0) {
#pragma unroll
    for (int r = 0; r < 16; r++) {
      int q = (r & 3) + 8 * (r >> 2) + 4 * hi;
      float a0 = o0[r] + red[qh * 2048 + q * 64 + ln];
      float a1 = o1[r] + red[qh * 2048 + q * 64 + 32 + ln];
      size_t base = ((size_t)(b * SS + q0 + qh * 32 + q)) * DD + h * HDIM;
      out[base + ln] = a0;
      out[base + 32 + ln] = a1;
    }
  }
}

extern "C" void kernel_launch(void* const* d_in, const int* in_sizes, int n_in,
                              void* d_out, int out_size, void* d_ws, size_t ws_size,
                              hipStream_t stream) {
  const float* x  = (const float*)d_in[0];
  const float* wq = (const float*)d_in[1];
  const float* bq = (const float*)d_in[2];
  const float* wk = (const float*)d_in[3];
  const float* bk = (const float*)d_in[4];
  const float* wv = (const float*)d_in[5];
  const float* bv = (const float*)d_in[6];
  float* out = (float*)d_out;

  constexpr size_t XN = (size_t)BB * SS * DD;  // 2,097,152 per projection output

  unsigned short* qo = (unsigned short*)d_ws;
  unsigned short* ko = qo + XN;
  unsigned short* vt = ko + XN;  // 12.6 MB total ws use

  proj_kernel<<<dim3(32, 4, 3), 256, 0, stream>>>(x, wq, wk, wv, bq, bk, bv, qo, ko, vt);
  attn_kernel<<<dim3(SS / 64, BB * HH), 256, 0, stream>>>(qo, ko, vt, out);
}

// Round 3
// 142.444 us; speedup vs baseline: 1.2226x; 1.0169x over previous
//
#include <hip/hip_runtime.h>
#include <cstdint>
#include <cstddef>

// Problem constants
#define BB   2
#define SS   2048
#define DD   512
#define HH   8
#define HDIM 64

typedef __attribute__((ext_vector_type(8)))  short          s16x8;
typedef __attribute__((ext_vector_type(8)))  unsigned short u16x8;
typedef __attribute__((ext_vector_type(16))) float          f32x16;

static __device__ __forceinline__ unsigned short f2bf(float f) {
  union { float f; unsigned u; } x; x.f = f;
  unsigned r = x.u + 0x7fffu + ((x.u >> 16) & 1u);  // RNE
  return (unsigned short)(r >> 16);
}
static __device__ __forceinline__ unsigned packbf(float a, float b) {
  return (unsigned)f2bf(a) | ((unsigned)f2bf(b) << 16);
}

// ---------------- fused cvt + QKV projection ---------------------------------------
// grid (M/128=32, N/64=8, 3); 256 threads = 4 waves, each wave 32 rows x 64 cols.
// 32x32x16 bf16 MFMA. Register-prefetch + LDS double-buffer, ONE barrier per K-iter.
// q,k -> bf16 head-split [B][H][S][HD]; v -> TRANSPOSED [B][H][HD][S].
// Q pre-scaled by 1/sqrt(HD)=0.125. n-tile(64) == one head => h = blockIdx.y.
__global__ __launch_bounds__(256) void proj_kernel(
    const float* __restrict__ x,
    const float* __restrict__ wq, const float* __restrict__ wk, const float* __restrict__ wv,
    const float* __restrict__ bq, const float* __restrict__ bk, const float* __restrict__ bv,
    unsigned short* __restrict__ qo, unsigned short* __restrict__ ko,
    unsigned short* __restrict__ vt) {
  __shared__ unsigned short As[2][128 * 40];  // 128 x 32 bf16, pad->40
  __shared__ unsigned short Bs[2][64 * 40];   //  64 x 32 bf16, pad->40

  const int z = blockIdx.z;
  const float* w; const float* bias;
  if (z == 0)      { w = wq; bias = bq; }
  else if (z == 1) { w = wk; bias = bk; }
  else             { w = wv; bias = bv; }

  const int t = threadIdx.x;
  const int lane = t & 63, wave = t >> 6;
  const int ln = lane & 31, hi = lane >> 5;
  const int m0 = blockIdx.x * 128, n0 = blockIdx.y * 64;

  // staging ownership: A has 1024 float4 chunks (4/thread), B has 512 (2/thread)
  float4 ar[4], br[2];
#pragma unroll
  for (int i = 0; i < 4; i++) {
    int c = t + i * 256;
    ar[i] = *(const float4*)&x[(size_t)(m0 + (c >> 3)) * DD + (c & 7) * 4];
  }
#pragma unroll
  for (int i = 0; i < 2; i++) {
    int c = t + i * 256;
    br[i] = *(const float4*)&w[(size_t)(n0 + (c >> 3)) * DD + (c & 7) * 4];
  }
#pragma unroll
  for (int i = 0; i < 4; i++) {
    int c = t + i * 256;
    ushort4 u; u.x = f2bf(ar[i].x); u.y = f2bf(ar[i].y); u.z = f2bf(ar[i].z); u.w = f2bf(ar[i].w);
    *(ushort4*)&As[0][(c >> 3) * 40 + (c & 7) * 4] = u;
  }
#pragma unroll
  for (int i = 0; i < 2; i++) {
    int c = t + i * 256;
    ushort4 u; u.x = f2bf(br[i].x); u.y = f2bf(br[i].y); u.z = f2bf(br[i].z); u.w = f2bf(br[i].w);
    *(ushort4*)&Bs[0][(c >> 3) * 40 + (c & 7) * 4] = u;
  }
  __syncthreads();

  f32x16 acc0 = {}, acc1 = {};

#pragma unroll 2
  for (int kt = 0; kt < 16; kt++) {
    const int cur = kt & 1, nxt = cur ^ 1;
    if (kt < 15) {  // prefetch next fp32 tile into registers (no LDS dependence)
      int k0 = (kt + 1) * 32;
#pragma unroll
      for (int i = 0; i < 4; i++) {
        int c = t + i * 256;
        ar[i] = *(const float4*)&x[(size_t)(m0 + (c >> 3)) * DD + k0 + (c & 7) * 4];
      }
#pragma unroll
      for (int i = 0; i < 2; i++) {
        int c = t + i * 256;
        br[i] = *(const float4*)&w[(size_t)(n0 + (c >> 3)) * DD + k0 + (c & 7) * 4];
      }
    }
    // compute from current buffer
#pragma unroll
    for (int c = 0; c < 2; c++) {
      s16x8 af = *(const s16x8*)&As[cur][(wave * 32 + ln) * 40 + c * 16 + hi * 8];
      s16x8 b0 = *(const s16x8*)&Bs[cur][(ln) * 40 + c * 16 + hi * 8];
      s16x8 b1 = *(const s16x8*)&Bs[cur][(32 + ln) * 40 + c * 16 + hi * 8];
      acc0 = __builtin_amdgcn_mfma_f32_32x32x16_bf16(af, b0, acc0, 0, 0, 0);
      acc1 = __builtin_amdgcn_mfma_f32_32x32x16_bf16(af, b1, acc1, 0, 0, 0);
    }
    if (kt < 15) {  // convert + stage into the other buffer (overlaps with next compute)
#pragma unroll
      for (int i = 0; i < 4; i++) {
        int c = t + i * 256;
        ushort4 u; u.x = f2bf(ar[i].x); u.y = f2bf(ar[i].y); u.z = f2bf(ar[i].z); u.w = f2bf(ar[i].w);
        *(ushort4*)&As[nxt][(c >> 3) * 40 + (c & 7) * 4] = u;
      }
#pragma unroll
      for (int i = 0; i < 2; i++) {
        int c = t + i * 256;
        ushort4 u; u.x = f2bf(br[i].x); u.y = f2bf(br[i].y); u.z = f2bf(br[i].z); u.w = f2bf(br[i].w);
        *(ushort4*)&Bs[nxt][(c >> 3) * 40 + (c & 7) * 4] = u;
      }
    }
    __syncthreads();
  }

  // Epilogue. C layout: col = ln (n), row = (r&3) + 8*(r>>2) + 4*hi (m).
  const float scale = (z == 0) ? 0.125f : 1.0f;
  const int h = blockIdx.y;
  const int bidx = m0 >> 11;
  const int sbase = (m0 & 2047) + wave * 32;
  unsigned short* dst = (z == 0) ? qo : ko;
#pragma unroll
  for (int nh = 0; nh < 2; nh++) {
    f32x16 a = nh ? acc1 : acc0;
    float bval = bias[n0 + nh * 32 + ln];
    int hd = nh * 32 + ln;
    if (z < 2) {
#pragma unroll
      for (int r = 0; r < 16; r++) {
        int s = sbase + (r & 3) + 8 * (r >> 2) + 4 * hi;
        dst[(((size_t)(bidx * HH + h) * SS) + s) * HDIM + hd] = f2bf((a[r] + bval) * scale);
      }
    } else {  // V transposed: [B][H][HD][S]; s,s+1 adjacent -> dword stores
      size_t rowbase = (((size_t)(bidx * HH + h) * HDIM) + hd) * SS;
#pragma unroll
      for (int g = 0; g < 4; g++) {
#pragma unroll
        for (int j = 0; j < 4; j += 2) {
          int s = sbase + 8 * g + 4 * hi + j;
          *(unsigned*)&vt[rowbase + s] = packbf(a[g * 4 + j] + bval, a[g * 4 + j + 1] + bval);
        }
      }
    }
  }
}

// ---------------- fused sigmoid attention (32x32x16 MFMA) ---------------------------
// grid (S/64, B*H); 256 threads = 4 waves: wave = (qhalf, khalf), 32q x 32k each.
// LDS double-buffered K/V (ONE barrier per tile); P C->A-layout transform done
// in-register via lane^32 shfl of packed bf16 pairs (no LDS round-trip).
__global__ __launch_bounds__(256) void attn_kernel(
    const unsigned short* __restrict__ qb,
    const unsigned short* __restrict__ kb,
    const unsigned short* __restrict__ vtb,
    float* __restrict__ out) {
  __shared__ unsigned short ks[2][64 * 72];  // K tile [key][d]
  __shared__ unsigned short vs[2][64 * 72];  // V^T tile [d][key]
  float* red = (float*)&ks[0][0];            // 16 KB alias for final O reduction

  const int t = threadIdx.x;
  const int lane = t & 63, wave = t >> 6;
  const int ln = lane & 31, hi = lane >> 5;
  const int qh = wave & 1, kh = wave >> 1;
  const int bh = blockIdx.y;
  const int b = bh >> 3, h = bh & 7;
  const unsigned short* qp = qb + (size_t)bh * SS * HDIM;
  const unsigned short* kp = kb + (size_t)bh * SS * HDIM;
  const unsigned short* vp = vtb + (size_t)bh * HDIM * SS;
  const int q0 = blockIdx.x * 64;

  // Q fragments in regs for whole kernel: B[n=q][k=d]
  s16x8 qf[4];
  {
    const int qrow = q0 + qh * 32 + ln;
#pragma unroll
    for (int c = 0; c < 4; c++)
      qf[c] = *(const s16x8*)&qp[(size_t)qrow * HDIM + c * 16 + hi * 8];
  }

  f32x16 o0 = {}, o1 = {};

  // staging: 512 x 16B chunks per array, 2 per thread
  u16x8 kr[2], vr[2];
#pragma unroll
  for (int i = 0; i < 2; i++) {
    int c = t + i * 256;
    int row = c >> 3, off = (c & 7) * 8;
    kr[i] = *(const u16x8*)&kp[(size_t)row * HDIM + off];
    vr[i] = *(const u16x8*)&vp[(size_t)row * SS + off];
  }
#pragma unroll
  for (int i = 0; i < 2; i++) {
    int c = t + i * 256;
    int row = c >> 3, off = (c & 7) * 8;
    *(u16x8*)&ks[0][row * 72 + off] = kr[i];
    *(u16x8*)&vs[0][row * 72 + off] = vr[i];
  }
  __syncthreads();

#pragma unroll 2
  for (int kt = 0; kt < 32; kt++) {
    const int cur = kt & 1, nxt = cur ^ 1;
    if (kt < 31) {  // prefetch next tile into registers
      int k0n = (kt + 1) * 64;
#pragma unroll
      for (int i = 0; i < 2; i++) {
        int c = t + i * 256;
        int row = c >> 3, off = (c & 7) * 8;
        kr[i] = *(const u16x8*)&kp[(size_t)(k0n + row) * HDIM + off];
        vr[i] = *(const u16x8*)&vp[(size_t)row * SS + k0n + off];
      }
    }

    // QK^T: st = S^T[key = kh*32 + rowpat][q = qh*32 + ln]
    f32x16 st = {};
#pragma unroll
    for (int c = 0; c < 4; c++) {
      s16x8 kf = *(const s16x8*)&ks[cur][(kh * 32 + ln) * 72 + c * 16 + hi * 8];
      st = __builtin_amdgcn_mfma_f32_32x32x16_bf16(kf, qf[c], st, 0, 0, 0);
    }

    // sigmoid -> packed bf16 pairs, grouped by r-quad g: pg[g] = keys {8g+4hi .. +3}
    unsigned pgx[4], pgy[4];
#pragma unroll
    for (int g = 0; g < 4; g++) {
      float s0 = 1.0f / (1.0f + __expf(-st[4 * g + 0]));
      float s1 = 1.0f / (1.0f + __expf(-st[4 * g + 1]));
      float s2 = 1.0f / (1.0f + __expf(-st[4 * g + 2]));
      float s3 = 1.0f / (1.0f + __expf(-st[4 * g + 3]));
      pgx[g] = packbf(s0, s1);
      pgy[g] = packbf(s2, s3);
    }

    // PV: build A-operand P-frags via lane^32 exchange.
    // frag(c,hi): keys 16c+8hi+{0..7}; j0..3 from hi'=0 lane's group g=2c+hi,
    // j4..7 from hi'=1 lane's same group.
#pragma unroll
    for (int c = 0; c < 2; c++) {
      int gk = 2 * c + hi, gs = 2 * c + (hi ^ 1);
      unsigned rx = __shfl_xor((int)pgx[gs], 32, 64);
      unsigned ry = __shfl_xor((int)pgy[gs], 32, 64);
      union { unsigned u[4]; s16x8 v; } pu;
      pu.u[0] = hi ? rx : pgx[gk];
      pu.u[1] = hi ? ry : pgy[gk];
      pu.u[2] = hi ? pgx[gk] : rx;
      pu.u[3] = hi ? pgy[gk] : ry;
      s16x8 vf0 = *(const s16x8*)&vs[cur][(ln) * 72 + kh * 32 + c * 16 + hi * 8];
      s16x8 vf1 = *(const s16x8*)&vs[cur][(32 + ln) * 72 + kh * 32 + c * 16 + hi * 8];
      o0 = __builtin_amdgcn_mfma_f32_32x32x16_bf16(pu.v, vf0, o0, 0, 0, 0);
      o1 = __builtin_amdgcn_mfma_f32_32x32x16_bf16(pu.v, vf1, o1, 0, 0, 0);
    }

    if (kt < 31) {  // stage prefetched tile into the other LDS buffer
#pragma unroll
      for (int i = 0; i < 2; i++) {
        int c = t + i * 256;
        int row = c >> 3, off = (c & 7) * 8;
        *(u16x8*)&ks[nxt][row * 72 + off] = kr[i];
        *(u16x8*)&vs[nxt][row * 72 + off] = vr[i];
      }
    }
    __syncthreads();
  }

  // reduce O over khalf pairs through LDS (aliases ks — dead after final barrier)
  if (kh == 1) {
#pragma unroll
    for (int r = 0; r < 16; r++) {
      int q = (r & 3) + 8 * (r >> 2) + 4 * hi;
      red[qh * 2048 + q * 64 + ln] = o0[r];
      red[qh * 2048 + q * 64 + 32 + ln] = o1[r];
    }
  }
  __syncthreads();
  if (kh == 0) {
#pragma unroll
    for (int r = 0; r < 16; r++) {
      int q = (r & 3) + 8 * (r >> 2) + 4 * hi;
      float a0 = o0[r] + red[qh * 2048 + q * 64 + ln];
      float a1 = o1[r] + red[qh * 2048 + q * 64 + 32 + ln];
      size_t base = ((size_t)(b * SS + q0 + qh * 32 + q)) * DD + h * HDIM;
      out[base + ln] = a0;
      out[base + 32 + ln] = a1;
    }
  }
}

extern "C" void kernel_launch(void* const* d_in, const int* in_sizes, int n_in,
                              void* d_out, int out_size, void* d_ws, size_t ws_size,
                              hipStream_t stream) {
  const float* x  = (const float*)d_in[0];
  const float* wq = (const float*)d_in[1];
  const float* bq = (const float*)d_in[2];
  const float* wk = (const float*)d_in[3];
  const float* bk = (const float*)d_in[4];
  const float* wv = (const float*)d_in[5];
  const float* bv = (const float*)d_in[6];
  float* out = (float*)d_out;

  constexpr size_t XN = (size_t)BB * SS * DD;

  unsigned short* qo = (unsigned short*)d_ws;
  unsigned short* ko = qo + XN;
  unsigned short* vt = ko + XN;  // 12 MB total ws use

  proj_kernel<<<dim3(32, 8, 3), 256, 0, stream>>>(x, wq, wk, wv, bq, bk, bv, qo, ko, vt);
  attn_kernel<<<dim3(SS / 64, BB * HH), 256, 0, stream>>>(qo, ko, vt, out);
}

// Round 4
// 125.323 us; speedup vs baseline: 1.3897x; 1.1366x over previous
//
#include <hip/hip_runtime.h>
#include <cstdint>
#include <cstddef>

// Problem constants
#define BB   2
#define SS   2048
#define DD   512
#define HH   8
#define HDIM 64

typedef __attribute__((ext_vector_type(8)))  short          s16x8;
typedef __attribute__((ext_vector_type(8)))  unsigned short u16x8;
typedef __attribute__((ext_vector_type(16))) float          f32x16;

static __device__ __forceinline__ unsigned short f2bf(float f) {
  union { float f; unsigned u; } x; x.f = f;
  unsigned r = x.u + 0x7fffu + ((x.u >> 16) & 1u);  // RNE
  return (unsigned short)(r >> 16);
}
// truncating bf16 pack: result = bf(hi)<<16 | bf(lo), ONE v_perm_b32
static __device__ __forceinline__ unsigned packtrunc(float lo, float hi) {
  return __builtin_amdgcn_perm(__float_as_uint(hi), __float_as_uint(lo), 0x07060302u);
}

// sigmoid scale folded into Q: -1/sqrt(64) * log2(e)
#define QSCALE (-0.18033688011111543f)

// ---------------- fused cvt + QKV projection ---------------------------------------
// grid (M/128=32, N/64=8, 3); 256 threads = 4 waves, each wave 32 rows x 64 cols.
// 32x32x16 bf16 MFMA. Register-prefetch + LDS double-buffer, ONE barrier per K-iter.
// q,k -> bf16 head-split [B][H][S][HD]; v -> TRANSPOSED [B][H][HD][S].
// Q pre-scaled by QSCALE (sigmoid becomes rcp(1+exp2(s)) in attn).
__global__ __launch_bounds__(256) void proj_kernel(
    const float* __restrict__ x,
    const float* __restrict__ wq, const float* __restrict__ wk, const float* __restrict__ wv,
    const float* __restrict__ bq, const float* __restrict__ bk, const float* __restrict__ bv,
    unsigned short* __restrict__ qo, unsigned short* __restrict__ ko,
    unsigned short* __restrict__ vt) {
  __shared__ unsigned short As[2][128 * 40];  // 128 x 32 bf16, pad->40
  __shared__ unsigned short Bs[2][64 * 40];   //  64 x 32 bf16, pad->40

  const int z = blockIdx.z;
  const float* w; const float* bias;
  if (z == 0)      { w = wq; bias = bq; }
  else if (z == 1) { w = wk; bias = bk; }
  else             { w = wv; bias = bv; }

  const int t = threadIdx.x;
  const int lane = t & 63, wave = t >> 6;
  const int ln = lane & 31, hi = lane >> 5;
  const int m0 = blockIdx.x * 128, n0 = blockIdx.y * 64;

  float4 ar[4], br[2];
#pragma unroll
  for (int i = 0; i < 4; i++) {
    int c = t + i * 256;
    ar[i] = *(const float4*)&x[(size_t)(m0 + (c >> 3)) * DD + (c & 7) * 4];
  }
#pragma unroll
  for (int i = 0; i < 2; i++) {
    int c = t + i * 256;
    br[i] = *(const float4*)&w[(size_t)(n0 + (c >> 3)) * DD + (c & 7) * 4];
  }
#pragma unroll
  for (int i = 0; i < 4; i++) {
    int c = t + i * 256;
    uint2 u; u.x = packtrunc(ar[i].x, ar[i].y); u.y = packtrunc(ar[i].z, ar[i].w);
    *(uint2*)&As[0][(c >> 3) * 40 + (c & 7) * 4] = u;
  }
#pragma unroll
  for (int i = 0; i < 2; i++) {
    int c = t + i * 256;
    uint2 u; u.x = packtrunc(br[i].x, br[i].y); u.y = packtrunc(br[i].z, br[i].w);
    *(uint2*)&Bs[0][(c >> 3) * 40 + (c & 7) * 4] = u;
  }
  __syncthreads();

  f32x16 acc0 = {}, acc1 = {};

#pragma unroll 2
  for (int kt = 0; kt < 16; kt++) {
    const int cur = kt & 1, nxt = cur ^ 1;
    if (kt < 15) {
      int k0 = (kt + 1) * 32;
#pragma unroll
      for (int i = 0; i < 4; i++) {
        int c = t + i * 256;
        ar[i] = *(const float4*)&x[(size_t)(m0 + (c >> 3)) * DD + k0 + (c & 7) * 4];
      }
#pragma unroll
      for (int i = 0; i < 2; i++) {
        int c = t + i * 256;
        br[i] = *(const float4*)&w[(size_t)(n0 + (c >> 3)) * DD + k0 + (c & 7) * 4];
      }
    }
#pragma unroll
    for (int c = 0; c < 2; c++) {
      s16x8 af = *(const s16x8*)&As[cur][(wave * 32 + ln) * 40 + c * 16 + hi * 8];
      s16x8 b0 = *(const s16x8*)&Bs[cur][(ln) * 40 + c * 16 + hi * 8];
      s16x8 b1 = *(const s16x8*)&Bs[cur][(32 + ln) * 40 + c * 16 + hi * 8];
      acc0 = __builtin_amdgcn_mfma_f32_32x32x16_bf16(af, b0, acc0, 0, 0, 0);
      acc1 = __builtin_amdgcn_mfma_f32_32x32x16_bf16(af, b1, acc1, 0, 0, 0);
    }
    if (kt < 15) {
#pragma unroll
      for (int i = 0; i < 4; i++) {
        int c = t + i * 256;
        uint2 u; u.x = packtrunc(ar[i].x, ar[i].y); u.y = packtrunc(ar[i].z, ar[i].w);
        *(uint2*)&As[nxt][(c >> 3) * 40 + (c & 7) * 4] = u;
      }
#pragma unroll
      for (int i = 0; i < 2; i++) {
        int c = t + i * 256;
        uint2 u; u.x = packtrunc(br[i].x, br[i].y); u.y = packtrunc(br[i].z, br[i].w);
        *(uint2*)&Bs[nxt][(c >> 3) * 40 + (c & 7) * 4] = u;
      }
    }
    __syncthreads();
  }

  // Epilogue. C layout: col = ln (n), row = (r&3) + 8*(r>>2) + 4*hi (m).
  const float scale = (z == 0) ? QSCALE : 1.0f;
  const int h = blockIdx.y;
  const int bidx = m0 >> 11;
  const int sbase = (m0 & 2047) + wave * 32;
  unsigned short* dst = (z == 0) ? qo : ko;
#pragma unroll
  for (int nh = 0; nh < 2; nh++) {
    f32x16 a = nh ? acc1 : acc0;
    float bval = bias[n0 + nh * 32 + ln];
    int hd = nh * 32 + ln;
    if (z < 2) {
#pragma unroll
      for (int r = 0; r < 16; r++) {
        int s = sbase + (r & 3) + 8 * (r >> 2) + 4 * hi;
        dst[(((size_t)(bidx * HH + h) * SS) + s) * HDIM + hd] = f2bf((a[r] + bval) * scale);
      }
    } else {  // V transposed: [B][H][HD][S]; s,s+1 adjacent -> dword stores
      size_t rowbase = (((size_t)(bidx * HH + h) * HDIM) + hd) * SS;
#pragma unroll
      for (int g = 0; g < 4; g++) {
#pragma unroll
        for (int j = 0; j < 4; j += 2) {
          int s = sbase + 8 * g + 4 * hi + j;
          unsigned pk = (unsigned)f2bf(a[g * 4 + j] + bval) |
                        ((unsigned)f2bf(a[g * 4 + j + 1] + bval) << 16);
          *(unsigned*)&vt[rowbase + s] = pk;
        }
      }
    }
  }
}

// ---------------- fused sigmoid attention: NO LDS in K-loop -------------------------
// grid (S/64=32, B*H=16); 256 threads = 4 waves; block = 64 queries; each wave owns
// a disjoint quarter of keys (16 tiles of 32, strided by 4). K/V fragments loaded
// DIRECTLY from global (coalesced dwordx4, L1/L2-served), register double-buffered.
// Zero barriers in the loop; single LDS pass for the 4-way O reduction at the end.
__global__ __launch_bounds__(256, 2) void attn_kernel(
    const unsigned short* __restrict__ qb,
    const unsigned short* __restrict__ kb,
    const unsigned short* __restrict__ vtb,
    float* __restrict__ out) {
  __shared__ __align__(16) float red[4 * 4096];  // 64 KB: per-wave O partials

  const int t = threadIdx.x;
  const int lane = t & 63, wave = t >> 6;
  const int ln = lane & 31, hi = lane >> 5;
  // XCD swizzle: same bh -> block ids congruent mod 16 -> same XCD (round-robin %8)
  const int fid = blockIdx.y * 32 + blockIdx.x;
  const int bh = fid & 15, qx = fid >> 4;
  const int b = bh >> 3, h = bh & 7;
  const unsigned short* qp = qb + (size_t)bh * SS * HDIM;
  const unsigned short* kp = kb + (size_t)bh * SS * HDIM;
  const unsigned short* vp = vtb + (size_t)bh * HDIM * SS;
  const int q0 = qx * 64;

  // Q fragments (B-operand: n=q on lane, k=d on regs), whole kernel in regs
  s16x8 qf[2][4];
#pragma unroll
  for (int qs = 0; qs < 2; qs++)
#pragma unroll
    for (int c = 0; c < 4; c++)
      qf[qs][c] = *(const s16x8*)&qp[(size_t)(q0 + qs * 32 + ln) * HDIM + c * 16 + hi * 8];

  f32x16 o00 = {}, o01 = {}, o10 = {}, o11 = {};

  // K frag: A[m=key][k=d]  addr (kt*32+ln)*64 + c*16 + hi*8
  // V frag: B[n=d][k=key]  addr (dh*32+ln)*2048 + kt*32 + c*16 + hi*8
  s16x8 kf[2][4], vf[2][4];
  int koff = (wave * 32 + ln) * HDIM + hi * 8;
  int voff = ln * SS + wave * 32 + hi * 8;
#pragma unroll
  for (int c = 0; c < 4; c++) kf[0][c] = *(const s16x8*)&kp[koff + c * 16];
#pragma unroll
  for (int c = 0; c < 2; c++) {
    vf[0][c]     = *(const s16x8*)&vp[voff + c * 16];
    vf[0][2 + c] = *(const s16x8*)&vp[voff + 32 * SS + c * 16];
  }
  koff += 4 * 32 * HDIM;  // next tile for this wave: keys += 128
  voff += 128;

#pragma unroll 2
  for (int i = 0; i < 16; i++) {
    const int cur = i & 1, nxt = cur ^ 1;
    if (i < 15) {  // prefetch next tile's fragments (no barrier, no LDS)
#pragma unroll
      for (int c = 0; c < 4; c++) kf[nxt][c] = *(const s16x8*)&kp[koff + c * 16];
#pragma unroll
      for (int c = 0; c < 2; c++) {
        vf[nxt][c]     = *(const s16x8*)&vp[voff + c * 16];
        vf[nxt][2 + c] = *(const s16x8*)&vp[voff + 32 * SS + c * 16];
      }
      koff += 4 * 32 * HDIM;
      voff += 128;
    }

    // QK^T: S^T[key_local on (r,hi)][q on ln], two q-subtiles
    f32x16 st0 = {}, st1 = {};
#pragma unroll
    for (int c = 0; c < 4; c++) {
      st0 = __builtin_amdgcn_mfma_f32_32x32x16_bf16(kf[cur][c], qf[0][c], st0, 0, 0, 0);
      st1 = __builtin_amdgcn_mfma_f32_32x32x16_bf16(kf[cur][c], qf[1][c], st1, 0, 0, 0);
    }

    // sigmoid = rcp(1 + exp2(st)) (scale folded into Q), truncating bf16 pack
    unsigned pgx[2][4], pgy[2][4];
#pragma unroll
    for (int qs = 0; qs < 2; qs++) {
      f32x16 stq = qs ? st1 : st0;
#pragma unroll
      for (int g = 0; g < 4; g++) {
        float p0 = __builtin_amdgcn_rcpf(1.0f + __builtin_amdgcn_exp2f(stq[4 * g + 0]));
        float p1 = __builtin_amdgcn_rcpf(1.0f + __builtin_amdgcn_exp2f(stq[4 * g + 1]));
        float p2 = __builtin_amdgcn_rcpf(1.0f + __builtin_amdgcn_exp2f(stq[4 * g + 2]));
        float p3 = __builtin_amdgcn_rcpf(1.0f + __builtin_amdgcn_exp2f(stq[4 * g + 3]));
        pgx[qs][g] = packtrunc(p0, p1);
        pgy[qs][g] = packtrunc(p2, p3);
      }
    }

    // PV: A-operand P built via lane^32 exchange (validated R3 pattern)
#pragma unroll
    for (int c = 0; c < 2; c++) {
      const int gk = 2 * c + hi, gs = 2 * c + (hi ^ 1);
#pragma unroll
      for (int qs = 0; qs < 2; qs++) {
        unsigned rx = __shfl_xor((int)pgx[qs][gs], 32, 64);
        unsigned ry = __shfl_xor((int)pgy[qs][gs], 32, 64);
        union { unsigned u[4]; s16x8 v; } pu;
        pu.u[0] = hi ? rx : pgx[qs][gk];
        pu.u[1] = hi ? ry : pgy[qs][gk];
        pu.u[2] = hi ? pgx[qs][gk] : rx;
        pu.u[3] = hi ? pgy[qs][gk] : ry;
        if (qs == 0) {
          o00 = __builtin_amdgcn_mfma_f32_32x32x16_bf16(pu.v, vf[cur][c], o00, 0, 0, 0);
          o01 = __builtin_amdgcn_mfma_f32_32x32x16_bf16(pu.v, vf[cur][2 + c], o01, 0, 0, 0);
        } else {
          o10 = __builtin_amdgcn_mfma_f32_32x32x16_bf16(pu.v, vf[cur][c], o10, 0, 0, 0);
          o11 = __builtin_amdgcn_mfma_f32_32x32x16_bf16(pu.v, vf[cur][2 + c], o11, 0, 0, 0);
        }
      }
    }
  }

  // 4-way cross-wave O reduction via LDS (only LDS use in the kernel)
#pragma unroll
  for (int qs = 0; qs < 2; qs++)
#pragma unroll
    for (int dh = 0; dh < 2; dh++) {
      f32x16 ov = qs ? (dh ? o11 : o10) : (dh ? o01 : o00);
#pragma unroll
      for (int r = 0; r < 16; r++) {
        int ql = qs * 32 + (r & 3) + 8 * (r >> 2) + 4 * hi;
        red[wave * 4096 + ql * 64 + dh * 32 + ln] = ov[r];
      }
    }
  __syncthreads();
  const float4* red4 = (const float4*)red;
#pragma unroll
  for (int j = 0; j < 4; j++) {
    int g = t + j * 256;
    float4 s0 = red4[g], s1 = red4[1024 + g], s2 = red4[2048 + g], s3 = red4[3072 + g];
    float4 s;
    s.x = s0.x + s1.x + s2.x + s3.x;
    s.y = s0.y + s1.y + s2.y + s3.y;
    s.z = s0.z + s1.z + s2.z + s3.z;
    s.w = s0.w + s1.w + s2.w + s3.w;
    int q = g >> 4, dbase = (g & 15) * 4;
    *(float4*)&out[((size_t)(b * SS + q0 + q)) * DD + h * HDIM + dbase] = s;
  }
}

extern "C" void kernel_launch(void* const* d_in, const int* in_sizes, int n_in,
                              void* d_out, int out_size, void* d_ws, size_t ws_size,
                              hipStream_t stream) {
  const float* x  = (const float*)d_in[0];
  const float* wq = (const float*)d_in[1];
  const float* bq = (const float*)d_in[2];
  const float* wk = (const float*)d_in[3];
  const float* bk = (const float*)d_in[4];
  const float* wv = (const float*)d_in[5];
  const float* bv = (const float*)d_in[6];
  float* out = (float*)d_out;

  constexpr size_t XN = (size_t)BB * SS * DD;

  unsigned short* qo = (unsigned short*)d_ws;
  unsigned short* ko = qo + XN;
  unsigned short* vt = ko + XN;  // 12 MB total ws use

  proj_kernel<<<dim3(32, 8, 3), 256, 0, stream>>>(x, wq, wk, wv, bq, bk, bv, qo, ko, vt);
  attn_kernel<<<dim3(SS / 64, BB * HH), 256, 0, stream>>>(qo, ko, vt, out);
}